// Round 5
// baseline (1135.542 us; speedup 1.0000x reference)
//
#include <hip/hip_runtime.h>
#include <math.h>

#define E_TOTAL   1000000
#define HDIM      128
#define K1        256   // 2H
#define N1        512   // 4H
#define N2        128   // H
#define M_TILE    64
#define BLOCK     256
#define GRID_P    1536  // persistent blocks (3/CU resident, ~10 tiles each)

typedef _Float16 f16;
typedef _Float16 f16_4  __attribute__((ext_vector_type(4)));
typedef _Float16 f16_8  __attribute__((ext_vector_type(8)));
typedef float    f32_16 __attribute__((ext_vector_type(16)));
typedef unsigned int u32;

// async global->LDS DMA, 16B/lane; dest MUST be wave-uniform base + lane*16
#define GLD_LDS16(srcp, dstp) __builtin_amdgcn_global_load_lds( \
    (const __attribute__((address_space(1))) u32*)(const void*)(srcp), \
    (__attribute__((address_space(3))) u32*)(void*)(dstp), 16, 0, 0)

// ---------------- prep kernels ----------------
// 32x32x16 fragment packing (A/B frag: lane l holds [row=l&31][k=(l>>5)*8+v]):
// W1F[nt(16)][kc(16)][lane(64)][v(8)] = W1[k=kc*16+(l>>5)*8+v][n=nt*32+(l&31)]
// W2F[nt(4)][kcg(32)][lane(64)][v(8)] = W2[k=kcg*16+(l>>5)*8+v][n=nt*32+(l&31)]
__global__ void prep_weights(const float* __restrict__ W1, const float* __restrict__ W2,
                             f16* __restrict__ W1F, f16* __restrict__ W2F) {
    int t = blockIdx.x * blockDim.x + threadIdx.x;
    const int total1 = K1 * N1;           // 131072
    const int total2 = N1 * N2;           // 65536
    if (t < total1) {
        int v    = t & 7;
        int lane = (t >> 3) & 63;
        int kc   = (t >> 9) & 15;
        int nt   = t >> 13;
        int k = kc * 16 + (lane >> 5) * 8 + v;
        int n = nt * 32 + (lane & 31);
        W1F[t] = (f16)W1[k * N1 + n];
    } else if (t < total1 + total2) {
        int u = t - total1;
        int v    = u & 7;
        int lane = (u >> 3) & 63;
        int kcg  = (u >> 9) & 31;
        int nt   = u >> 14;
        int k = kcg * 16 + (lane >> 5) * 8 + v;
        int n = nt * 32 + (lane & 31);
        W2F[u] = (f16)W2[k * N2 + n];
    }
}

__global__ void prep_emb(const float* __restrict__ emb, f16* __restrict__ emb16) {
    int t = blockIdx.x * blockDim.x + threadIdx.x;   // 3.2M threads, 4 elems each
    float4 f = ((const float4*)emb)[t];
    f16_4 v = { (f16)f.x, (f16)f.y, (f16)f.z, (f16)f.w };
    ((f16_4*)emb16)[t] = v;
}

// ---------------- main kernel ----------------
// R13 = R10 compute (proven 499us) + persistent blocks + async DMA gather.
//  - grid 1536 persistent; each block loops ~10 e-tiles.
//  - phase0 replaced by 8x global_load_lds(16B) per wave: wave wnt owns
//    (met=wnt>>1, side=wnt&1), fills sAF rows wnt*8+s (wave-uniform dest,
//    per-lane source emb16[node(l&31)] + s*16 + lh*8). Issued for tile t+1
//    right after tile t's LAST sAF read (q=3 post-kc barrier); lands during
//    P2-final/epilogues/phase3. Zero staging VGPRs, zero scatter conflicts.
//  - sH2F overlays sBF (sAF must stay DMA-writable until loop top).
//  - barriers downstream of the DMA issue are raw s_barrier + lgkmcnt(0)
//    so hipcc's vmcnt(0)-before-s_barrier drain doesn't stall the DMA.
//  LDS 48KB -> 3 blocks/CU; VGPR ~R10 level -> launch_bounds(256,3).
template <bool F16EMB>
__global__ __launch_bounds__(BLOCK, 3) void edge_mlp_kernel(
    const float* __restrict__ emb,
    const f16*   __restrict__ emb16,
    const int*   __restrict__ eidx,
    const f16*   __restrict__ W1F,
    const float* __restrict__ b1,
    const f16*   __restrict__ W2F,
    const float* __restrict__ b2,
    const float* __restrict__ W3,
    const float* __restrict__ b3,
    float* __restrict__ out)
{
    __shared__ __align__(16) f16 sAF[2 * 16 * 64 * 8];      // 32 KB (DMA dest)
    __shared__ __align__(16) f16 sBF[2 * 8 * 64 * 8];       // 16 KB
    f16* sH2F = sBF;                                        // 16 KB overlay

    const int tid  = threadIdx.x;
    const int wnt  = tid >> 6;     // wave 0..3
    const int lane = tid & 63;
    const int l31  = lane & 31;
    const int lh   = lane >> 5;    // 0/1
    const int met  = wnt >> 1;     // edge-tile half this wave gathers
    const int side = wnt & 1;      // col/row table this wave gathers
    const int NT   = E_TOTAL / M_TILE;   // 15625

    // ---- prologue: DMA-gather tile0 ----
    if (F16EMB) {
        const int nd = eidx[side * E_TOTAL + blockIdx.x * M_TILE + met * 32 + l31];
        const f16* nrow = emb16 + (size_t)nd * HDIM;
        #pragma unroll
        for (int s = 0; s < 8; ++s)
            GLD_LDS16(nrow + s * 16 + lh * 8, sAF + (wnt * 8 + s) * 512);
    }

    for (int tile = blockIdx.x; tile < NT; tile += GRID_P) {
        const int e0 = tile * M_TILE;

        if (F16EMB) {
            asm volatile("s_waitcnt vmcnt(0)" ::: "memory");   // own DMA done
            __builtin_amdgcn_s_barrier();                      // publish all rows
            __builtin_amdgcn_sched_barrier(0);
        } else {
            // fallback: staged gather each tile (compat path)
            __syncthreads();
            const int m    = tid >> 2;
            const int sd   = (tid >> 1) & 1;
            const int sub  = tid & 1;
            const int mt   = m >> 5;
            const int m31  = m & 31;
            const int node = eidx[sd * E_TOTAL + e0 + m];
            const float* src = emb + (size_t)node * HDIM;
            #pragma unroll
            for (int j = 0; j < 4; ++j) {
                const int g    = sd * 8 + sub * 4 + j;
                const int koff = (sub * 4 + j) * 16;
                #pragma unroll
                for (int q2 = 0; q2 < 2; ++q2) {
                    float4 fa = *(const float4*)(src + koff + q2 * 8);
                    float4 fb = *(const float4*)(src + koff + q2 * 8 + 4);
                    f16_8 v = { (f16)fa.x, (f16)fa.y, (f16)fa.z, (f16)fa.w,
                                (f16)fb.x, (f16)fb.y, (f16)fb.z, (f16)fb.w };
                    *(f16_8*)(sAF + (((mt * 16 + g) * 64 + q2 * 32 + m31) << 3)) = v;
                }
            }
            __syncthreads();
        }

        // prefetch next tile's node index (consumed ~6K cyc later at DMA issue)
        const int tnext = tile + GRID_P;
        int ndn = 0;
        if (F16EMB && tnext < NT)
            ndn = eidx[side * E_TOTAL + tnext * M_TILE + met * 32 + l31];

        f32_16 acc2[2] = {{0.f}, {0.f}};   // P2 accumulators (both edge tiles)

        // ---- Region 0: P1(0) only -> sBF ----
        {
            f32_16 acc1[2] = {{0.f}, {0.f}};
            const int nt = wnt;                          // quarter 0
            #pragma unroll
            for (int kc = 0; kc < 16; ++kc) {
                f16_8 wf = *(const f16_8*)(W1F + (((nt * 16 + kc) * 64 + lane) << 3));
                #pragma unroll
                for (int et = 0; et < 2; ++et) {
                    f16_8 ef = *(const f16_8*)(sAF + (((et * 16 + kc) * 64 + lane) << 3));
                    acc1[et] = __builtin_amdgcn_mfma_f32_32x32x16_f16(wf, ef, acc1[et], 0, 0, 0);
                }
            }
            #pragma unroll
            for (int et = 0; et < 2; ++et) {
                #pragma unroll
                for (int g = 0; g < 4; ++g) {
                    const int wnl = wnt * 32 + lh * 4 + g * 8;
                    const float4 bv = *(const float4*)(b1 + wnl);
                    f16_4 hv;
                    #pragma unroll
                    for (int i = 0; i < 4; ++i) {
                        float v = acc1[et][g * 4 + i] + ((const float*)&bv)[i];
                        hv[i] = (f16)(v > 0.f ? v : 0.f);
                    }
                    const int kl = wnt * 2 + (g >> 1);
                    *(f16_4*)(sBF + ((((et * 8 + kl) * 64 + (g & 1) * 32 + l31) << 3) + lh * 4)) = hv;
                }
            }
        }
        __syncthreads();

        // ---- Regions 1..3: kc{P1(q) + P2(q-1)<-sBF}; bar; H1(q)->sBF; bar ----
        #pragma unroll
        for (int q = 1; q < 4; ++q) {
            f32_16 acc1[2] = {{0.f}, {0.f}};
            const int nt = q * 4 + wnt;
            #pragma unroll
            for (int kc = 0; kc < 16; ++kc) {
                f16_8 wf = *(const f16_8*)(W1F + (((nt * 16 + kc) * 64 + lane) << 3));
                #pragma unroll
                for (int et = 0; et < 2; ++et) {
                    f16_8 ef = *(const f16_8*)(sAF + (((et * 16 + kc) * 64 + lane) << 3));
                    acc1[et] = __builtin_amdgcn_mfma_f32_32x32x16_f16(wf, ef, acc1[et], 0, 0, 0);
                }
                if (kc < 8) {
                    const int kcg = (q - 1) * 8 + kc;
                    f16_8 wf2 = *(const f16_8*)(W2F + (((wnt * 32 + kcg) * 64 + lane) << 3));
                    #pragma unroll
                    for (int et = 0; et < 2; ++et) {
                        f16_8 ef2 = *(const f16_8*)(sBF + (((et * 8 + kc) * 64 + lane) << 3));
                        acc2[et] = __builtin_amdgcn_mfma_f32_32x32x16_f16(wf2, ef2, acc2[et], 0, 0, 0);
                    }
                }
            }
            __syncthreads();    // all P2(q-1) sBF reads AND (q=3) all sAF reads done

            if (q == 3 && F16EMB && tnext < NT) {
                // issue next tile's gather; lands during P2-final/epilogue/phase3
                __builtin_amdgcn_sched_barrier(0);
                const f16* nrow = emb16 + (size_t)ndn * HDIM;
                #pragma unroll
                for (int s = 0; s < 8; ++s)
                    GLD_LDS16(nrow + s * 16 + lh * 8, sAF + (wnt * 8 + s) * 512);
            }

            // P1(q) epilogue -> sBF (single buffer)
            #pragma unroll
            for (int et = 0; et < 2; ++et) {
                #pragma unroll
                for (int g = 0; g < 4; ++g) {
                    const int wnl = wnt * 32 + lh * 4 + g * 8;
                    const float4 bv = *(const float4*)(b1 + q * 128 + wnl);
                    f16_4 hv;
                    #pragma unroll
                    for (int i = 0; i < 4; ++i) {
                        float v = acc1[et][g * 4 + i] + ((const float*)&bv)[i];
                        hv[i] = (f16)(v > 0.f ? v : 0.f);
                    }
                    const int kl = wnt * 2 + (g >> 1);
                    *(f16_4*)(sBF + ((((et * 8 + kl) * 64 + (g & 1) * 32 + l31) << 3) + lh * 4)) = hv;
                }
            }
            if (q < 3) {
                __syncthreads();
            } else {
                // raw barrier: publish sBF writes WITHOUT draining the DMA vmcnt
                asm volatile("s_waitcnt lgkmcnt(0)" ::: "memory");
                __builtin_amdgcn_s_barrier();
                __builtin_amdgcn_sched_barrier(0);
            }
        }

        // ---- Final P2(3) <- sBF ----
        {
            #pragma unroll
            for (int kc = 0; kc < 8; ++kc) {
                const int kcg = 24 + kc;
                f16_8 wf2 = *(const f16_8*)(W2F + (((wnt * 32 + kcg) * 64 + lane) << 3));
                #pragma unroll
                for (int et = 0; et < 2; ++et) {
                    f16_8 ef2 = *(const f16_8*)(sBF + (((et * 8 + kc) * 64 + lane) << 3));
                    acc2[et] = __builtin_amdgcn_mfma_f32_32x32x16_f16(wf2, ef2, acc2[et], 0, 0, 0);
                }
            }
        }
        // raw barrier: all waves' sBF reads retired (by data dep) -> safe to overlay
        __builtin_amdgcn_s_barrier();
        __builtin_amdgcn_sched_barrier(0);

        // ---- P2 epilogue -> sH2F (overlays sBF) ----
        {
            #pragma unroll
            for (int et = 0; et < 2; ++et) {
                #pragma unroll
                for (int g = 0; g < 4; ++g) {
                    const int wn = wnt * 32 + lh * 4 + g * 8;
                    const float4 bv = *(const float4*)(b2 + wn);
                    f16_4 hv;
                    #pragma unroll
                    for (int i = 0; i < 4; ++i) {
                        float v = acc2[et][g * 4 + i] + ((const float*)&bv)[i];
                        hv[i] = (f16)(v > 0.f ? v : 0.f);
                    }
                    const int kl = wnt * 2 + (g >> 1);
                    *(f16_4*)(sH2F + ((((et * 8 + kl) * 64 + (g & 1) * 32 + l31) << 3) + lh * 4)) = hv;
                }
            }
        }
        asm volatile("s_waitcnt lgkmcnt(0)" ::: "memory");   // publish sH2F
        __builtin_amdgcn_s_barrier();
        __builtin_amdgcn_sched_barrier(0);

        // ---- Phase 3: logit = H2 @ W3 + b3 ; sigmoid ----
        {
            const int m   = tid >> 2;
            const int j   = tid & 3;
            const int mt  = m >> 5;
            const int m31 = m & 31;
            float s = 0.f;
            #pragma unroll
            for (int jj = 0; jj < 2; ++jj) {
                const int kl = j * 2 + jj;
                f16_8 a = *(const f16_8*)(sH2F + (((mt * 8 + kl) * 64 + m31) << 3));
                f16_8 b = *(const f16_8*)(sH2F + (((mt * 8 + kl) * 64 + 32 + m31) << 3));
                const float4* w3v = (const float4*)(W3 + kl * 16);
                float4 w0 = w3v[0], w1 = w3v[1], w2 = w3v[2], w3q = w3v[3];
                s += (float)a[0]*w0.x + (float)a[1]*w0.y + (float)a[2]*w0.z + (float)a[3]*w0.w;
                s += (float)a[4]*w1.x + (float)a[5]*w1.y + (float)a[6]*w1.z + (float)a[7]*w1.w;
                s += (float)b[0]*w2.x + (float)b[1]*w2.y + (float)b[2]*w2.z + (float)b[3]*w2.w;
                s += (float)b[4]*w3q.x + (float)b[5]*w3q.y + (float)b[6]*w3q.z + (float)b[7]*w3q.w;
            }
            s += __shfl_xor(s, 1);
            s += __shfl_xor(s, 2);
            if (j == 0) {
                const float logit = s + b3[0];
                out[e0 + m] = 1.0f / (1.0f + __expf(-logit));
            }
        }
        // loop top provides the barrier before sBF/sAF are rewritten
    }
}

extern "C" void kernel_launch(void* const* d_in, const int* in_sizes, int n_in,
                              void* d_out, int out_size, void* d_ws, size_t ws_size,
                              hipStream_t stream) {
    const float* emb  = (const float*)d_in[0];
    const int*   eidx = (const int*)d_in[1];
    const float* W1   = (const float*)d_in[2];
    const float* b1   = (const float*)d_in[3];
    const float* W2   = (const float*)d_in[4];
    const float* b2   = (const float*)d_in[5];
    const float* W3   = (const float*)d_in[6];
    const float* b3   = (const float*)d_in[7];
    float* out = (float*)d_out;

    const size_t wbytes   = (size_t)(K1 * N1 + N1 * N2) * sizeof(f16);   // 384 KB
    const size_t embbytes = (size_t)100000 * HDIM * sizeof(f16);         // 25.6 MB

    f16* W1F = (f16*)d_ws;
    f16* W2F = W1F + K1 * N1;

    const int prep_total = K1 * N1 + N1 * N2;
    prep_weights<<<(prep_total + 255) / 256, 256, 0, stream>>>(W1, W2, W1F, W2F);

    if (ws_size >= wbytes + embbytes) {
        f16* emb16 = W2F + N1 * N2;
        const int cvt_threads = 100000 * HDIM / 4;   // 3.2M
        prep_emb<<<cvt_threads / 256, 256, 0, stream>>>(emb, emb16);
        edge_mlp_kernel<true><<<GRID_P, BLOCK, 0, stream>>>(
            emb, emb16, eidx, W1F, b1, W2F, b2, W3, b3, out);
    } else {
        edge_mlp_kernel<false><<<GRID_P, BLOCK, 0, stream>>>(
            emb, (const f16*)nullptr, eidx, W1F, b1, W2F, b2, W3, b3, out);
    }
}